// Round 8
// baseline (2104.030 us; speedup 1.0000x reference)
//
#include <hip/hip_runtime.h>
#include <math.h>

#define NN 50000
#define NE 800000
#define FIN 197
#define KIN 224          // FIN zero-padded to multiple of 32
#define H 256
#define HEADS 8
#define HD 32
#define LAYERS 5
#define FF 1024
#define INV_SCALE 0.17677669529663687f   // 1/sqrt(32)

typedef __attribute__((ext_vector_type(8))) short short8;
typedef __attribute__((ext_vector_type(4))) float f32x4;
typedef unsigned short ushort;

// fast GELU via exp2/rcp (max abs err ~3e-4 vs exact erf form)
__device__ __forceinline__ float gelu_f(float x) {
    float x2 = x * x;
    float u = __builtin_fmaf(0.044715f * x2, x, x);
    float e = __builtin_amdgcn_exp2f(-2.3022075f * u);
    return x * __builtin_amdgcn_rcpf(1.0f + e);
}
__device__ __forceinline__ ushort f2b(float f) {        // fp32 -> bf16 RNE
    unsigned u = __float_as_uint(f);
    u += 0x7fffu + ((u >> 16) & 1u);
    return (ushort)(u >> 16);
}
__device__ __forceinline__ float b2f(ushort b) {
    return __uint_as_float(((unsigned)b) << 16);
}
__device__ __forceinline__ float dot2b(unsigned a, unsigned b) {  // 2 packed bf16 pairs
    float a0 = __uint_as_float(a << 16), a1 = __uint_as_float(a & 0xffff0000u);
    float b0 = __uint_as_float(b << 16), b1 = __uint_as_float(b & 0xffff0000u);
    return a0 * b0 + a1 * b1;
}

// async global->LDS 16B per lane; LDS dest = wave-uniform base + lane*16
__device__ __forceinline__ void load16_lds(const ushort* gp, ushort* lp) {
    __builtin_amdgcn_global_load_lds(
        (const __attribute__((address_space(1))) unsigned int*)gp,
        (__attribute__((address_space(3))) unsigned int*)lp,
        16, 0, 0);
}

// ---------------- MFMA bf16 GEMM: C = act(A @ Bt^T + bias) + res ----------------
// Round-16 (VERIFIED): 32x64 wave-tile, chunk-XOR both-sides swizzle, ~20
// waves/CU. Round-18 (VERIFIED, -282us): LDS-staged wide-store epilogue.
// Round-19: counted-vmcnt depth-2 pipeline (T3+T4 minimal port). The r16 loop
// consumed tile t's loads ONE iteration after issue (~100-200cy age vs
// 200-400cy L2/L3 latency) -> every K-iteration stalled at the barrier drain.
// Now: 3-buffer rotation; stage(t+2) at end of iter t; per iter:
//   s_waitcnt vmcnt(3)  (own tile-t loads landed; t+1's stay IN FLIGHT)
//   s_barrier           (raw -- no compiler vmcnt(0) drain)
//   ds_read + MFMA      (compiler manages lgkmcnt)
//   s_barrier           (all waves done reading tile t)
//   stage(t+2)          (writes buffer last read at iter t-1 -- race-free)
// Never drains vmcnt to 0 in the main loop (T4). Epilogue unchanged: uses
// wave-private As[0]/As[1] slices after the final vmcnt(0) iteration.
__global__ __launch_bounds__(256) void gemm_bf16_kernel(
    const ushort* __restrict__ A, int lda,
    const ushort* __restrict__ Bt,
    const float* __restrict__ bias,
    const float* __restrict__ res, int ldr,
    float* __restrict__ Cf, ushort* __restrict__ Cb, int ldc,
    int n, int K, int act, int gx)   // gx = N/64 col-tiles
{
    __shared__ ushort As[3][128 * 32];   // 24 KB
    __shared__ ushort Bs[3][64 * 32];    // 12 KB
    int tid = threadIdx.x;
    int lane = tid & 63;
    int wave = tid >> 6;

    // swizzled block mapping: groups of (8 row-tiles x gx col-tiles)
    int tiles_y = (n + 127) >> 7;
    int lin = blockIdx.x;
    int gsz = gx * 8;
    int group = lin / gsz;
    int rem = lin - group * gsz;
    int rows_left = tiles_y - group * 8;
    int rg = rows_left < 8 ? rows_left : 8;
    int r = rem % rg;
    int c = rem / rg;
    int brow = (group * 8 + r) * 128;
    int bcol = c * 64;

    f32x4 acc[2][4] = {};
    int m0 = lane & 15;
    // swizzled read chunk offset (ushorts): chunk (lane>>4) XOR ((row>>1)&3);
    // row = base + m0 with base%16==0 so pattern reduces to (lane>>1)&3.
    int rdc = ((lane >> 4) ^ ((lane >> 1) & 3)) * 8;

    // per-lane staging coords: row-in-16 = lane>>2; source chunk = dest chunk
    // (lane&3) XOR ((row>>1)&3) = (lane&3) ^ ((lane>>3)&3)
    int rA = lane >> 2;
    int c8s = (((lane & 3) ^ ((lane >> 3) & 3)) * 8);

    long arow0, arow1, brow0;
    {
        int gr0 = brow + wave * 32 + rA;        if (gr0 >= n) gr0 = n - 1;
        int gr1 = brow + wave * 32 + 16 + rA;   if (gr1 >= n) gr1 = n - 1;
        arow0 = (long)gr0 * lda;
        arow1 = (long)gr1 * lda;
        brow0 = (long)(bcol + wave * 16 + rA) * K;
    }
    int loA0 = (wave * 32) * 32;
    int loA1 = (wave * 32 + 16) * 32;
    int loB  = (wave * 16) * 32;

    int nt = K >> 5;                     // >= 7 for all call sites
    // prologue: stage tiles 0 and 1 (6 loads in flight per wave)
    load16_lds(A + arow0 + c8s, &As[0][loA0]);
    load16_lds(A + arow1 + c8s, &As[0][loA1]);
    load16_lds(Bt + brow0 + c8s, &Bs[0][loB]);
    load16_lds(A + arow0 + 32 + c8s, &As[1][loA0]);
    load16_lds(A + arow1 + 32 + c8s, &As[1][loA1]);
    load16_lds(Bt + brow0 + 32 + c8s, &Bs[1][loB]);

    for (int t = 0; t < nt; ++t) {
        int p = t % 3;
        // wait for OWN tile-t loads; keep tile-t+1's in flight (counted, not 0)
        if (t + 1 < nt) asm volatile("s_waitcnt vmcnt(3)" ::: "memory");
        else            asm volatile("s_waitcnt vmcnt(0)" ::: "memory");
        __builtin_amdgcn_s_barrier();     // all waves' tile-t data in LDS
        short8 af[2], bfr[4];
        #pragma unroll
        for (int i = 0; i < 2; ++i)
            af[i] = *(const short8*)&As[p][(wave * 32 + i * 16 + m0) * 32 + rdc];
        #pragma unroll
        for (int j = 0; j < 4; ++j)
            bfr[j] = *(const short8*)&Bs[p][(j * 16 + m0) * 32 + rdc];
        #pragma unroll
        for (int i = 0; i < 2; ++i)
            #pragma unroll
            for (int j = 0; j < 4; ++j)
                acc[i][j] = __builtin_amdgcn_mfma_f32_16x16x32_bf16(af[i], bfr[j], acc[i][j], 0, 0, 0);
        __builtin_amdgcn_s_barrier();     // all waves done reading tile t
        if (t + 2 < nt) {                 // stage 2 tiles ahead
            int k0 = (t + 2) << 5;
            int p2 = (t + 2) % 3;
            load16_lds(A + arow0 + k0 + c8s, &As[p2][loA0]);
            load16_lds(A + arow1 + k0 + c8s, &As[p2][loA1]);
            load16_lds(Bt + brow0 + k0 + c8s, &Bs[p2][loB]);
        }
    }

    // ---- wide-store epilogue (wave-private As slices as staging) ----
    float* ep0 = (float*)&As[0][wave * 1024];   // 8 rows x 64 f32 = 2 KB
    float* ep1 = (float*)&As[1][wave * 1024];
    int ccol = lane & 15;
    int crow0 = (lane >> 4) * 4;                // local row base 0/4/8/12
    float* epw = (lane < 32) ? ep0 : ep1;       // rows 0-7 -> ep0, 8-15 -> ep1
    #pragma unroll
    for (int i = 0; i < 2; ++i) {
        int rowbase = brow + wave * 32 + i * 16;
        #pragma unroll
        for (int rr = 0; rr < 4; ++rr) {
            int r8 = (crow0 + rr) & 7;
            #pragma unroll
            for (int j = 0; j < 4; ++j)
                epw[r8 * 64 + j * 16 + ccol] = acc[i][j][rr];
        }
        #pragma unroll
        for (int pass = 0; pass < 2; ++pass) {
            const float* ep = pass ? ep1 : ep0;
            #pragma unroll
            for (int k = 0; k < 2; ++k) {
                int idx = k * 64 + lane;          // 0..127
                int lr  = idx >> 4;               // 0..7
                int c4  = (idx & 15) * 4;         // col (floats)
                int grow = rowbase + pass * 8 + lr;
                f32x4 v = *(const f32x4*)&ep[lr * 64 + c4];
                int gcol = bcol + c4;
                if (bias) {
                    float4 b4 = *(const float4*)(bias + gcol);
                    v[0] += b4.x; v[1] += b4.y; v[2] += b4.z; v[3] += b4.w;
                }
                if (act) {
                    v[0] = gelu_f(v[0]); v[1] = gelu_f(v[1]);
                    v[2] = gelu_f(v[2]); v[3] = gelu_f(v[3]);
                }
                if (grow < n) {
                    if (res) {
                        float4 r4 = *(const float4*)(res + (long)grow * ldr + gcol);
                        v[0] += r4.x; v[1] += r4.y; v[2] += r4.z; v[3] += r4.w;
                    }
                    if (Cf) *(f32x4*)(Cf + (long)grow * ldc + gcol) = v;
                    if (Cb) {
                        ushort4 ob = { f2b(v[0]), f2b(v[1]), f2b(v[2]), f2b(v[3]) };
                        *(ushort4*)(Cb + (long)grow * ldc + gcol) = ob;
                    }
                }
            }
        }
    }
}

// ---------------- LayerNorm rows of 256; input fp32 (af) or bf16 (ab) ----------------
__global__ __launch_bounds__(256) void ln256_kernel(
    const float* __restrict__ af, const ushort* __restrict__ ab,
    const float* __restrict__ res,
    const float* __restrict__ g, const float* __restrict__ bta,
    float* __restrict__ outf, ushort* __restrict__ outb, int n, int post_gelu)
{
    int row = blockIdx.x * 4 + (threadIdx.x >> 6);
    if (row >= n) return;
    int lane = threadIdx.x & 63;
    float4 v;
    if (af) {
        v = *(const float4*)(af + (long)row * H + lane * 4);
    } else {
        ushort4 vb = *(const ushort4*)(ab + (long)row * H + lane * 4);
        v.x = b2f(vb.x); v.y = b2f(vb.y); v.z = b2f(vb.z); v.w = b2f(vb.w);
    }
    if (res) {
        float4 r = *(const float4*)(res + (long)row * H + lane * 4);
        v.x += r.x; v.y += r.y; v.z += r.z; v.w += r.w;
    }
    float s = v.x + v.y + v.z + v.w;
    #pragma unroll
    for (int off = 1; off < 64; off <<= 1) s += __shfl_xor(s, off);
    float mean = s * (1.0f / H);
    float dx = v.x - mean, dy = v.y - mean, dz = v.z - mean, dw = v.w - mean;
    float qs = dx * dx + dy * dy + dz * dz + dw * dw;
    #pragma unroll
    for (int off = 1; off < 64; off <<= 1) qs += __shfl_xor(qs, off);
    float rstd = rsqrtf(qs * (1.0f / H) + 1e-5f);
    float4 gg = *(const float4*)(g + lane * 4);
    float4 bb = *(const float4*)(bta + lane * 4);
    float4 o;
    o.x = dx * rstd * gg.x + bb.x;
    o.y = dy * rstd * gg.y + bb.y;
    o.z = dz * rstd * gg.z + bb.z;
    o.w = dw * rstd * gg.w + bb.w;
    if (post_gelu) { o.x = gelu_f(o.x); o.y = gelu_f(o.y); o.z = gelu_f(o.z); o.w = gelu_f(o.w); }
    if (outf) *(float4*)(outf + (long)row * H + lane * 4) = o;
    if (outb) {
        ushort4 ob = { f2b(o.x), f2b(o.y), f2b(o.z), f2b(o.w) };
        *(ushort4*)(outb + (long)row * H + lane * 4) = ob;
    }
}

// ---------------- conversions ----------------
__global__ __launch_bounds__(256) void xcast_kernel(const float* __restrict__ x,
                                                    ushort* __restrict__ xb)
{
    long i = (long)blockIdx.x * 256 + threadIdx.x;
    if (i >= (long)NN * KIN) return;
    int n = (int)(i / KIN), c = (int)(i % KIN);
    xb[i] = (c < FIN) ? f2b(x[(long)n * FIN + c]) : (ushort)0;
}

__global__ __launch_bounds__(256) void wtin_kernel(const float* __restrict__ W,
                                                   ushort* __restrict__ Wt)
{
    int i = blockIdx.x * 256 + threadIdx.x;
    if (i >= 256 * KIN) return;
    int m = i / KIN, k = i % KIN;
    Wt[i] = (k < FIN) ? f2b(W[(long)k * H + m]) : (ushort)0;
}

__global__ __launch_bounds__(256) void wtqkv_kernel(
    const float* __restrict__ Wq, const float* __restrict__ Wk,
    const float* __restrict__ Wv, ushort* __restrict__ out)
{
    long i = (long)blockIdx.x * 256 + threadIdx.x;
    if (i >= (long)LAYERS * 768 * 256) return;
    int l = (int)(i / (768 * 256));
    int r = (int)(i % (768 * 256));
    int m = r >> 8, k = r & 255;
    const float* W = (m < 256) ? Wq : ((m < 512) ? Wk : Wv);
    out[i] = f2b(W[(long)l * 65536 + (long)k * 256 + (m & 255)]);
}

__global__ __launch_bounds__(256) void wtgen_kernel(
    const float* __restrict__ W, ushort* __restrict__ out, int L, int K, int M)
{
    long i = (long)blockIdx.x * 256 + threadIdx.x;
    if (i >= (long)L * K * M) return;
    int l = (int)(i / ((long)K * M));
    int r = (int)(i % ((long)K * M));
    int m = r / K, k = r % K;
    out[i] = f2b(W[(long)l * K * M + (long)k * M + m]);
}

// ---------------- CSR build ----------------
__global__ __launch_bounds__(256) void deg_kernel(const int* __restrict__ dst,
                                                   int* __restrict__ deg)
{
    int e = blockIdx.x * 256 + threadIdx.x;
    if (e >= NE) return;
    atomicAdd(&deg[dst[e]], 1);
}

__global__ __launch_bounds__(256) void scan1_kernel(const int* __restrict__ deg,
                                                     int* __restrict__ rowptr,
                                                     int* __restrict__ bsum)
{
    __shared__ int buf[256];
    int tid = threadIdx.x;
    int i = blockIdx.x * 256 + tid;
    int v = (i < NN) ? deg[i] : 0;
    buf[tid] = v;
    __syncthreads();
    #pragma unroll
    for (int off = 1; off < 256; off <<= 1) {
        int t = (tid >= off) ? buf[tid - off] : 0;
        __syncthreads();
        buf[tid] += t;
        __syncthreads();
    }
    if (i < NN) rowptr[i] = buf[tid] - v;
    if (tid == 255) bsum[blockIdx.x] = buf[255];
}

__global__ __launch_bounds__(256) void scan2_kernel(int* __restrict__ bsum, int nb)
{
    __shared__ int buf[256];
    int tid = threadIdx.x;
    int v = (tid < nb) ? bsum[tid] : 0;
    buf[tid] = v;
    __syncthreads();
    #pragma unroll
    for (int off = 1; off < 256; off <<= 1) {
        int t = (tid >= off) ? buf[tid - off] : 0;
        __syncthreads();
        buf[tid] += t;
        __syncthreads();
    }
    if (tid < nb) bsum[tid] = buf[tid] - v;
}

__global__ __launch_bounds__(256) void scan3_kernel(int* __restrict__ rowptr,
                                                     const int* __restrict__ bsum)
{
    int i = blockIdx.x * 256 + threadIdx.x;
    if (i < NN) rowptr[i] += bsum[blockIdx.x];
    if (i == 0) rowptr[NN] = NE;
}

__global__ __launch_bounds__(256) void fill_kernel(
    const int* __restrict__ src, const int* __restrict__ dst,
    const float* __restrict__ ea, const int* __restrict__ rowptr,
    int* __restrict__ cursor, int* __restrict__ csr_src,
    float2* __restrict__ csr_ea)
{
    int e = blockIdx.x * 256 + threadIdx.x;
    if (e >= NE) return;
    int d = dst[e];
    int pos = atomicAdd(&cursor[d], 1);
    int j = rowptr[d] + pos;
    csr_src[j] = src[e];
    csr_ea[j] = *(const float2*)(ea + 2 * e);
}

// ---------------- fused gather attention (one wave per node, all 8 heads) ----------------
// Depth-4 register prefetch, pairwise softmax, exp2-domain. Pinned at the
// random-gather L2-fill ceiling (~3.4 TB/s, FETCH 392MB constant across
// depth-2/depth-4/sorted variants). Only byte-reduction (fp8 K/V) remains --
// absmax-risky, parked.
#define LOADE(idx, kbuf, vbuf, ebuf)                                   \
    { int s_ = csr_src[idx]; ebuf = csr_ea[idx];                       \
      const ushort* kr_ = qkv + (long)s_ * 768 + 256;                  \
      kbuf = *(const uint2*)(kr_ + lane * 4);                          \
      vbuf = *(const uint2*)(kr_ + 256 + lane * 4); }

#define PAIR(k1, v1, e1, k2, v2, e2)                                               \
    { float p1 = dot2b(q2.x, (k1).x) + dot2b(q2.y, (k1).y);                        \
      float p2 = dot2b(q2.x, (k2).x) + dot2b(q2.y, (k2).y);                        \
      p1 += __shfl_xor(p1, 1);  p2 += __shfl_xor(p2, 1);                           \
      p1 += __shfl_xor(p1, 2);  p2 += __shfl_xor(p2, 2);                           \
      p1 += __shfl_xor(p1, 4);  p2 += __shfl_xor(p2, 4);                           \
      float s1 = p1 * c1 + (e1).x * w0 + (e1).y * w1 + bb;                         \
      float s2 = p2 * c1 + (e2).x * w0 + (e2).y * w1 + bb;                         \
      float mp = fmaxf(s1, s2);                                                    \
      float x1 = __builtin_amdgcn_exp2f(s1 - mp);                                  \
      float x2 = __builtin_amdgcn_exp2f(s2 - mp);                                  \
      float lp = x1 + x2;                                                          \
      float b0 = x1 * __uint_as_float((v1).x << 16)         + x2 * __uint_as_float((v2).x << 16);          \
      float b1 = x1 * __uint_as_float((v1).x & 0xffff0000u) + x2 * __uint_as_float((v2).x & 0xffff0000u);  \
      float b2 = x1 * __uint_as_float((v1).y << 16)         + x2 * __uint_as_float((v2).y << 16);          \
      float b3 = x1 * __uint_as_float((v1).y & 0xffff0000u) + x2 * __uint_as_float((v2).y & 0xffff0000u);  \
      float mn = fmaxf(m, mp);                                                     \
      float so = __builtin_amdgcn_exp2f(m - mn);                                   \
      float sp = __builtin_amdgcn_exp2f(mp - mn);                                  \
      l  = l  * so + lp * sp;                                                      \
      a0 = a0 * so + b0 * sp;                                                      \
      a1 = a1 * so + b1 * sp;                                                      \
      a2 = a2 * so + b2 * sp;                                                      \
      a3 = a3 * so + b3 * sp;                                                      \
      m = mn; }

#define SINGLE(kb, vb, eb)                                                         \
    { float p1 = dot2b(q2.x, (kb).x) + dot2b(q2.y, (kb).y);                        \
      p1 += __shfl_xor(p1, 1);                                                     \
      p1 += __shfl_xor(p1, 2);                                                     \
      p1 += __shfl_xor(p1, 4);                                                     \
      float s1 = p1 * c1 + (eb).x * w0 + (eb).y * w1 + bb;                         \
      float mn = fmaxf(m, s1);                                                     \
      float so = __builtin_amdgcn_exp2f(m - mn);                                   \
      float e_ = __builtin_amdgcn_exp2f(s1 - mn);                                  \
      l  = l  * so + e_;                                                           \
      a0 = a0 * so + e_ * __uint_as_float((vb).x << 16);                           \
      a1 = a1 * so + e_ * __uint_as_float((vb).x & 0xffff0000u);                   \
      a2 = a2 * so + e_ * __uint_as_float((vb).y << 16);                           \
      a3 = a3 * so + e_ * __uint_as_float((vb).y & 0xffff0000u);                   \
      m = mn; }

__global__ __launch_bounds__(256) void attn_kernel(
    const ushort* __restrict__ qkv,
    const int* __restrict__ rowptr, const int* __restrict__ csr_src,
    const float2* __restrict__ csr_ea,
    const float* __restrict__ We, const float* __restrict__ be,
    ushort* __restrict__ aggb)
{
    int node = blockIdx.x * 4 + (threadIdx.x >> 6);
    if (node >= NN) return;
    int lane = threadIdx.x & 63;
    int h = lane >> 3;                 // global head 0..7
    const float L2E = 1.4426950408889634f;
    float w0 = We[h] * L2E, w1 = We[8 + h] * L2E, bb = be[h] * L2E;
    const float c1 = INV_SCALE * L2E;

    uint2 q2 = *(const uint2*)(qkv + (long)node * 768 + lane * 4);
    int jbeg = rowptr[node], jend = rowptr[node + 1];

    float m = -1e30f, l = 0.f;
    float a0 = 0.f, a1 = 0.f, a2 = 0.f, a3 = 0.f;

    uint2 k0v = {0,0}, v0v = {0,0}, k1v = {0,0}, v1v = {0,0};
    uint2 k2v = {0,0}, v2v = {0,0}, k3v = {0,0}, v3v = {0,0};
    float2 e0v = {0.f,0.f}, e1v = {0.f,0.f}, e2v = {0.f,0.f}, e3v = {0.f,0.f};

    if (jbeg + 0 < jend) LOADE(jbeg + 0, k0v, v0v, e0v);
    if (jbeg + 1 < jend) LOADE(jbeg + 1, k1v, v1v, e1v);
    if (jbeg + 2 < jend) LOADE(jbeg + 2, k2v, v2v, e2v);
    if (jbeg + 3 < jend) LOADE(jbeg + 3, k3v, v3v, e3v);

    int j = jbeg;
    for (; j + 3 < jend; j += 4) {
        PAIR(k0v, v0v, e0v, k1v, v1v, e1v);          // edges j, j+1
        if (j + 4 < jend) LOADE(j + 4, k0v, v0v, e0v);
        if (j + 5 < jend) LOADE(j + 5, k1v, v1v, e1v);
        PAIR(k2v, v2v, e2v, k3v, v3v, e3v);          // edges j+2, j+3
        if (j + 6 < jend) LOADE(j + 6, k2v, v2v, e2v);
        if (j + 7 < jend) LOADE(j + 7, k3v, v3v, e3v);
    }
    int rleft = jend - j;                            // 0..3
    if (rleft >= 2) PAIR(k0v, v0v, e0v, k1v, v1v, e1v);
    if (rleft == 3) SINGLE(k2v, v2v, e2v);
    if (rleft == 1) SINGLE(k0v, v0v, e0v);

    float inv = 1.0f / (l + 1e-16f);
    ushort4 o = { f2b(a0 * inv), f2b(a1 * inv), f2b(a2 * inv), f2b(a3 * inv) };
    *(ushort4*)(aggb + (long)node * 256 + lane * 4) = o;
}

// ---------------- classifier tail ----------------
__global__ __launch_bounds__(256) void cls_kernel(
    const float* __restrict__ t1, const float* __restrict__ W,
    const float* __restrict__ b, float* __restrict__ out)
{
    int i = blockIdx.x * 256 + threadIdx.x;
    if (i >= NN) return;
    const float* tp = t1 + (long)i * 128;
    float a0 = 0.f, a1 = 0.f;
    #pragma unroll
    for (int j = 0; j < 128; j += 4) {
        float4 t = *(const float4*)(tp + j);
        a0 += t.x * W[(j + 0) * 2] + t.y * W[(j + 1) * 2] + t.z * W[(j + 2) * 2] + t.w * W[(j + 3) * 2];
        a1 += t.x * W[(j + 0) * 2 + 1] + t.y * W[(j + 1) * 2 + 1] + t.z * W[(j + 2) * 2 + 1] + t.w * W[(j + 3) * 2 + 1];
    }
    float l0 = a0 + b[0], l1 = a1 + b[1];
    out[(long)i * 2 + 0] = l0;
    out[(long)i * 2 + 1] = l1;
    float mx = fmaxf(l0, l1);
    float p0 = expf(l0 - mx), p1 = expf(l1 - mx);
    float sden = p0 + p1;
    out[2L * NN + (long)i * 2 + 0] = p0 / sden;
    out[2L * NN + (long)i * 2 + 1] = p1 / sden;
}

extern "C" void kernel_launch(void* const* d_in, const int* in_sizes, int n_in,
                              void* d_out, int out_size, void* d_ws, size_t ws_size,
                              hipStream_t stream) {
    const float* x      = (const float*)d_in[0];
    const int*   ei     = (const int*)d_in[1];
    const float* ea     = (const float*)d_in[2];
    const float* in_W   = (const float*)d_in[3];
    const float* in_b   = (const float*)d_in[4];
    const float* in_g   = (const float*)d_in[5];
    const float* in_bb  = (const float*)d_in[6];
    const float* Wq     = (const float*)d_in[7];
    const float* Wk     = (const float*)d_in[8];
    const float* Wv     = (const float*)d_in[9];
    const float* We     = (const float*)d_in[10];
    const float* be     = (const float*)d_in[11];
    const float* Wo     = (const float*)d_in[12];
    const float* bo     = (const float*)d_in[13];
    const float* ln1_g  = (const float*)d_in[14];
    const float* ln1_b  = (const float*)d_in[15];
    const float* ln2_g  = (const float*)d_in[16];
    const float* ln2_b  = (const float*)d_in[17];
    const float* f1_W   = (const float*)d_in[18];
    const float* f1_b   = (const float*)d_in[19];
    const float* f2_W   = (const float*)d_in[20];
    const float* f2_b   = (const float*)d_in[21];
    const float* cls1_W = (const float*)d_in[22];
    const float* cls1_b = (const float*)d_in[23];
    const float* cls2_W = (const float*)d_in[24];
    const float* cls2_b = (const float*)d_in[25];
    float* out = (float*)d_out;

    const int* src = ei;
    const int* dst = ei + NE;

    // ---- workspace layout (~197 MB) ----
    char* w = (char*)d_ws;
    float* B0 = (float*)w;            w += (size_t)NN * H * 4;       // h / out (fp32)
    ushort* hb = (ushort*)w;          w += (size_t)NN * H * 2;       // bf16 activations
    char* pool = w;                   w += (size_t)NN * 1024 * 2;    // 102.4 MB union
    ushort* qkv  = (ushort*)pool;                                    // N x 768 bf16
    ushort* aggb = (ushort*)(pool + (size_t)NN * 768 * 2);           // N x 256 bf16
    float*  tproj = (float*)pool;                                    // input-proj t
    ushort* xb   = (ushort*)(pool + (size_t)NN * H * 4);             // N x 224 bf16
    ushort* tb   = (ushort*)pool;                                    // FFN N x 1024 bf16
    float*  t1   = (float*)pool;                                     // cls hidden fp32
    int* deg    = (int*)w;            w += (size_t)NN * 4;
    int* cursor = (int*)w;            w += (size_t)NN * 4;
    int* rowptr = (int*)w;            w += (size_t)(NN + 2) * 4;
    int* bsum   = (int*)w;            w += 1024;
    int* csr_src = (int*)w;           w += (size_t)NE * 4;
    float2* csr_ea = (float2*)w;      w += (size_t)NE * 8;
    ushort* wqkv_t = (ushort*)w;      w += (size_t)LAYERS * 768 * 256 * 2;
    ushort* wo_t  = (ushort*)w;       w += (size_t)LAYERS * 65536 * 2;
    ushort* f1_t  = (ushort*)w;       w += (size_t)LAYERS * 262144 * 2;
    ushort* f2_t  = (ushort*)w;       w += (size_t)LAYERS * 262144 * 2;
    ushort* c1_t  = (ushort*)w;       w += (size_t)32768 * 2;
    ushort* inw_t = (ushort*)w;       w += (size_t)256 * KIN * 2;

    dim3 blk(256);
    const int ln_grid = (NN + 3) / 4;
    const int e_grid = (NE + 255) / 256;
    const int n_grid = (NN + 255) / 256;
    const int ty = (NN + 127) / 128;   // 128-row tiles

    // ---- CSR build ----
    hipMemsetAsync(deg, 0, (size_t)NN * 4, stream);
    hipMemsetAsync(cursor, 0, (size_t)NN * 4, stream);
    deg_kernel<<<e_grid, blk, 0, stream>>>(dst, deg);
    scan1_kernel<<<n_grid, blk, 0, stream>>>(deg, rowptr, bsum);
    scan2_kernel<<<1, blk, 0, stream>>>(bsum, n_grid);
    scan3_kernel<<<n_grid, blk, 0, stream>>>(rowptr, bsum);
    fill_kernel<<<e_grid, blk, 0, stream>>>(src, dst, ea, rowptr, cursor, csr_src, csr_ea);

    // ---- weight convert/transpose ----
    wtqkv_kernel<<<(int)(((long)LAYERS * 768 * 256 + 255) / 256), blk, 0, stream>>>(Wq, Wk, Wv, wqkv_t);
    wtgen_kernel<<<(int)(((long)LAYERS * 65536 + 255) / 256), blk, 0, stream>>>(Wo, wo_t, LAYERS, 256, 256);
    wtgen_kernel<<<(int)(((long)LAYERS * 262144 + 255) / 256), blk, 0, stream>>>(f1_W, f1_t, LAYERS, 256, 1024);
    wtgen_kernel<<<(int)(((long)LAYERS * 262144 + 255) / 256), blk, 0, stream>>>(f2_W, f2_t, LAYERS, 1024, 256);
    wtgen_kernel<<<(32768 + 255) / 256, blk, 0, stream>>>(cls1_W, c1_t, 1, 256, 128);
    wtin_kernel<<<(256 * KIN + 255) / 256, blk, 0, stream>>>(in_W, inw_t);

    // ---- input projection (MFMA) ----
    xcast_kernel<<<(int)(((long)NN * KIN + 255) / 256), blk, 0, stream>>>(x, xb);
    {
        gemm_bf16_kernel<<<4 * ty, blk, 0, stream>>>(xb, KIN, inw_t, in_b, nullptr, 0,
                                                     tproj, nullptr, H, NN, KIN, 0, 4);
        ln256_kernel<<<ln_grid, blk, 0, stream>>>(tproj, nullptr, nullptr, in_g, in_bb, B0, nullptr, NN, 1);
    }

    for (int l = 0; l < LAYERS; ++l) {
        const float* we  = We + (long)l * 16;
        const float* bel = be + (long)l * 8;
        const float* bol = bo + (long)l * H;
        const float* g1 = ln1_g + (long)l * H;
        const float* b1 = ln1_b + (long)l * H;
        const float* g2 = ln2_g + (long)l * H;
        const float* b2 = ln2_b + (long)l * H;
        const float* bf1 = f1_b + (long)l * FF;
        const float* bf2 = f2_b + (long)l * H;

        // hb = bf16(LN1(h))
        ln256_kernel<<<ln_grid, blk, 0, stream>>>(B0, nullptr, nullptr, g1, b1, nullptr, hb, NN, 0);

        // fused QKV (M=768) + 8-head gather attention
        gemm_bf16_kernel<<<12 * ty, blk, 0, stream>>>(hb, H, wqkv_t + (long)l * 768 * 256,
            nullptr, nullptr, 0, nullptr, qkv, 768, NN, H, 0, 12);
        attn_kernel<<<(NN + 3) / 4, blk, 0, stream>>>(qkv, rowptr, csr_src, csr_ea, we, bel, aggb);

        // B0 = LN(aggb@Wo^T + bo + h); hb = bf16(out)
        gemm_bf16_kernel<<<4 * ty, blk, 0, stream>>>(aggb, H, wo_t + (long)l * 65536,
            bol, nullptr, 0, nullptr, qkv, H, NN, H, 0, 4);   // reuse qkv head as woo
        ln256_kernel<<<ln_grid, blk, 0, stream>>>(nullptr, qkv, B0, g2, b2, B0, hb, NN, 0);

        // FFN one-shot: tb = gelu(hb@f1^T+b) bf16 ; B0 = tb@f2^T + b + B0
        gemm_bf16_kernel<<<16 * ty, blk, 0, stream>>>(hb, H, f1_t + (long)l * 262144,
            bf1, nullptr, 0, nullptr, tb, FF, NN, H, 1, 16);
        gemm_bf16_kernel<<<4 * ty, blk, 0, stream>>>(tb, FF, f2_t + (long)l * 262144,
            bf2, B0, H, B0, (l == LAYERS - 1) ? hb : nullptr, H, NN, FF, 0, 4);
    }

    // ---- classifier ----
    {
        gemm_bf16_kernel<<<2 * ty, blk, 0, stream>>>(hb, H, c1_t, cls1_b, nullptr, 0,
                                                     t1, nullptr, 128, NN, H, 1, 2);
        cls_kernel<<<n_grid, blk, 0, stream>>>(t1, cls2_W, cls2_b, out);
    }
}

// Round 9
// 2074.181 us; speedup vs baseline: 1.0144x; 1.0144x over previous
//
#include <hip/hip_runtime.h>
#include <math.h>

#define NN 50000
#define NE 800000
#define FIN 197
#define KIN 224          // FIN zero-padded to multiple of 32
#define H 256
#define HEADS 8
#define HD 32
#define LAYERS 5
#define FF 1024
#define INV_SCALE 0.17677669529663687f   // 1/sqrt(32)

typedef __attribute__((ext_vector_type(8))) short short8;
typedef __attribute__((ext_vector_type(4))) float f32x4;
typedef unsigned short ushort;

// fast GELU via exp2/rcp (max abs err ~3e-4 vs exact erf form)
__device__ __forceinline__ float gelu_f(float x) {
    float x2 = x * x;
    float u = __builtin_fmaf(0.044715f * x2, x, x);
    float e = __builtin_amdgcn_exp2f(-2.3022075f * u);
    return x * __builtin_amdgcn_rcpf(1.0f + e);
}
__device__ __forceinline__ ushort f2b(float f) {        // fp32 -> bf16 RNE
    unsigned u = __float_as_uint(f);
    u += 0x7fffu + ((u >> 16) & 1u);
    return (ushort)(u >> 16);
}
__device__ __forceinline__ float b2f(ushort b) {
    return __uint_as_float(((unsigned)b) << 16);
}
__device__ __forceinline__ float dot2b(unsigned a, unsigned b) {  // 2 packed bf16 pairs
    float a0 = __uint_as_float(a << 16), a1 = __uint_as_float(a & 0xffff0000u);
    float b0 = __uint_as_float(b << 16), b1 = __uint_as_float(b & 0xffff0000u);
    return a0 * b0 + a1 * b1;
}

// async global->LDS 16B per lane; LDS dest = wave-uniform base + lane*16
__device__ __forceinline__ void load16_lds(const ushort* gp, ushort* lp) {
    __builtin_amdgcn_global_load_lds(
        (const __attribute__((address_space(1))) unsigned int*)gp,
        (__attribute__((address_space(3))) unsigned int*)lp,
        16, 0, 0);
}

// ---------------- MFMA bf16 GEMM: C = act(A @ Bt^T + bias) + res ----------------
// Round-20. r19's counted-vmcnt pipeline was an EXACT null (2103->2104us):
// load age isn't the wall. Cycle audit: the 32x64 wave-tile reads 6KB LDS per
// 8 MFMAs (21.8 FLOP/LDS-byte) -- LDS operand bandwidth + per-block fixed cost
// over only 8 K-iters is the limiter. Changes:
//  (1) block tile 128x128 (wave-tile 32x128, acc[2][8]=64 AGPR, ~120 regs ->
//      4 waves/SIMD, 16 waves/CU): 10KB LDS per 16 MFMAs (26.2 FLOP/B, -37%
//      LDS traffic/FLOP), half the blocks (half the prologue overhead).
//  (2) revert to r18's 2-buffer __syncthreads loop (LDS 32KB).
//  (3) epilogue re-derived for 128-wide tile: 8KB/wave staging carved from
//      the four idle As/Bs slices (chunk = lane>>4; read-back chunk is
//      compile-time per unrolled k -- no scratch, rule 20). 512B segments.
__global__ __launch_bounds__(256) void gemm_bf16_kernel(
    const ushort* __restrict__ A, int lda,
    const ushort* __restrict__ Bt,
    const float* __restrict__ bias,
    const float* __restrict__ res, int ldr,
    float* __restrict__ Cf, ushort* __restrict__ Cb, int ldc,
    int n, int K, int act, int gx)   // gx = N/128 col-tiles
{
    __shared__ ushort As[2][128 * 32];   // 16 KB
    __shared__ ushort Bs[2][128 * 32];   // 16 KB
    int tid = threadIdx.x;
    int lane = tid & 63;
    int wave = tid >> 6;

    // swizzled block mapping: groups of (8 row-tiles x gx col-tiles)
    int tiles_y = (n + 127) >> 7;
    int lin = blockIdx.x;
    int gsz = gx * 8;
    int group = lin / gsz;
    int rem = lin - group * gsz;
    int rows_left = tiles_y - group * 8;
    int rg = rows_left < 8 ? rows_left : 8;
    int r = rem % rg;
    int c = rem / rg;
    int brow = (group * 8 + r) * 128;
    int bcol = c * 128;

    f32x4 acc[2][8] = {};
    int m0 = lane & 15;
    // swizzled read chunk offset (ushorts): chunk (lane>>4) XOR ((row>>1)&3);
    // row = base + m0 with base%16==0 so pattern reduces to (lane>>1)&3.
    int rdc = ((lane >> 4) ^ ((lane >> 1) & 3)) * 8;

    // per-lane staging coords: row-in-16 = lane>>2; source chunk = dest chunk
    // (lane&3) XOR ((row>>1)&3) = (lane&3) ^ ((lane>>3)&3)
    int rA = lane >> 2;
    int c8s = (((lane & 3) ^ ((lane >> 3) & 3)) * 8);

    long arow0, arow1, brow0, brow1;
    {
        int gr0 = brow + wave * 32 + rA;        if (gr0 >= n) gr0 = n - 1;
        int gr1 = brow + wave * 32 + 16 + rA;   if (gr1 >= n) gr1 = n - 1;
        arow0 = (long)gr0 * lda;
        arow1 = (long)gr1 * lda;
        brow0 = (long)(bcol + wave * 32 + rA) * K;
        brow1 = (long)(bcol + wave * 32 + 16 + rA) * K;
    }
    int lo0 = (wave * 32) * 32;
    int lo1 = (wave * 32 + 16) * 32;

    int nt = K >> 5;
    load16_lds(A + arow0 + c8s, &As[0][lo0]);
    load16_lds(A + arow1 + c8s, &As[0][lo1]);
    load16_lds(Bt + brow0 + c8s, &Bs[0][lo0]);
    load16_lds(Bt + brow1 + c8s, &Bs[0][lo1]);
    __syncthreads();

    for (int t = 0; t < nt; ++t) {
        int p = t & 1;
        if (t + 1 < nt) {                 // prefetch next K-tile into other buffer
            int k0 = (t + 1) << 5;
            load16_lds(A + arow0 + k0 + c8s, &As[p ^ 1][lo0]);
            load16_lds(A + arow1 + k0 + c8s, &As[p ^ 1][lo1]);
            load16_lds(Bt + brow0 + k0 + c8s, &Bs[p ^ 1][lo0]);
            load16_lds(Bt + brow1 + k0 + c8s, &Bs[p ^ 1][lo1]);
        }
        short8 af[2], bfr[8];
        #pragma unroll
        for (int i = 0; i < 2; ++i)
            af[i] = *(const short8*)&As[p][(wave * 32 + i * 16 + m0) * 32 + rdc];
        #pragma unroll
        for (int j = 0; j < 8; ++j)
            bfr[j] = *(const short8*)&Bs[p][(j * 16 + m0) * 32 + rdc];
        #pragma unroll
        for (int i = 0; i < 2; ++i)
            #pragma unroll
            for (int j = 0; j < 8; ++j)
                acc[i][j] = __builtin_amdgcn_mfma_f32_16x16x32_bf16(af[i], bfr[j], acc[i][j], 0, 0, 0);
        __syncthreads();                  // next buffer staged (drains vmcnt)
    }

    // ---- wide-store epilogue: 8KB/wave staging from the 4 idle buffer slices ----
    // 16 rows x 128 f32 per pass (2 passes: i=0 rows 0-15, i=1 rows 16-31 of
    // the wave's 32-row strip). chunk = 4 rows x 128 f32 = 2KB.
    float* ch0 = (float*)&As[0][wave * 1024];
    float* ch1 = (float*)&As[1][wave * 1024];
    float* ch2 = (float*)&Bs[0][wave * 1024];
    float* ch3 = (float*)&Bs[1][wave * 1024];
    int ccol = lane & 15;
    int mych = lane >> 4;                       // crow0 = mych*4 -> chunk = mych
    float* wch = (mych == 0) ? ch0 : ((mych == 1) ? ch1 : ((mych == 2) ? ch2 : ch3));
    int gcol = bcol + (lane & 31) * 4;
    #pragma unroll
    for (int i = 0; i < 2; ++i) {
        int rowbase = brow + wave * 32 + i * 16;
        #pragma unroll
        for (int rr = 0; rr < 4; ++rr)
            #pragma unroll
            for (int j = 0; j < 8; ++j)
                wch[rr * 128 + j * 16 + ccol] = acc[i][j][rr];
        // same-wave LDS write->read: in-order per wave (r18 epilogue relied on
        // the same property); compiler inserts lgkmcnt.
        #pragma unroll
        for (int k = 0; k < 8; ++k) {
            const float* rch = ((k >> 1) == 0) ? ch0 :
                               (((k >> 1) == 1) ? ch1 :
                               (((k >> 1) == 2) ? ch2 : ch3));   // compile-time
            f32x4 v = *(const f32x4*)&rch[(((k & 1) * 64) + lane) * 4];
            int grow = rowbase + 2 * k + (lane >> 5);
            if (bias) {
                float4 b4 = *(const float4*)(bias + gcol);
                v[0] += b4.x; v[1] += b4.y; v[2] += b4.z; v[3] += b4.w;
            }
            if (act) {
                v[0] = gelu_f(v[0]); v[1] = gelu_f(v[1]);
                v[2] = gelu_f(v[2]); v[3] = gelu_f(v[3]);
            }
            if (grow < n) {
                if (res) {
                    float4 r4 = *(const float4*)(res + (long)grow * ldr + gcol);
                    v[0] += r4.x; v[1] += r4.y; v[2] += r4.z; v[3] += r4.w;
                }
                if (Cf) *(f32x4*)(Cf + (long)grow * ldc + gcol) = v;
                if (Cb) {
                    ushort4 ob = { f2b(v[0]), f2b(v[1]), f2b(v[2]), f2b(v[3]) };
                    *(ushort4*)(Cb + (long)grow * ldc + gcol) = ob;
                }
            }
        }
        if (i == 0) __syncthreads();      // pass-1 rewrites slices; keep waves'
                                          // slice reuse race-free w/ own reads
    }
}

// ---------------- LayerNorm rows of 256; input fp32 (af) or bf16 (ab) ----------------
__global__ __launch_bounds__(256) void ln256_kernel(
    const float* __restrict__ af, const ushort* __restrict__ ab,
    const float* __restrict__ res,
    const float* __restrict__ g, const float* __restrict__ bta,
    float* __restrict__ outf, ushort* __restrict__ outb, int n, int post_gelu)
{
    int row = blockIdx.x * 4 + (threadIdx.x >> 6);
    if (row >= n) return;
    int lane = threadIdx.x & 63;
    float4 v;
    if (af) {
        v = *(const float4*)(af + (long)row * H + lane * 4);
    } else {
        ushort4 vb = *(const ushort4*)(ab + (long)row * H + lane * 4);
        v.x = b2f(vb.x); v.y = b2f(vb.y); v.z = b2f(vb.z); v.w = b2f(vb.w);
    }
    if (res) {
        float4 r = *(const float4*)(res + (long)row * H + lane * 4);
        v.x += r.x; v.y += r.y; v.z += r.z; v.w += r.w;
    }
    float s = v.x + v.y + v.z + v.w;
    #pragma unroll
    for (int off = 1; off < 64; off <<= 1) s += __shfl_xor(s, off);
    float mean = s * (1.0f / H);
    float dx = v.x - mean, dy = v.y - mean, dz = v.z - mean, dw = v.w - mean;
    float qs = dx * dx + dy * dy + dz * dz + dw * dw;
    #pragma unroll
    for (int off = 1; off < 64; off <<= 1) qs += __shfl_xor(qs, off);
    float rstd = rsqrtf(qs * (1.0f / H) + 1e-5f);
    float4 gg = *(const float4*)(g + lane * 4);
    float4 bb = *(const float4*)(bta + lane * 4);
    float4 o;
    o.x = dx * rstd * gg.x + bb.x;
    o.y = dy * rstd * gg.y + bb.y;
    o.z = dz * rstd * gg.z + bb.z;
    o.w = dw * rstd * gg.w + bb.w;
    if (post_gelu) { o.x = gelu_f(o.x); o.y = gelu_f(o.y); o.z = gelu_f(o.z); o.w = gelu_f(o.w); }
    if (outf) *(float4*)(outf + (long)row * H + lane * 4) = o;
    if (outb) {
        ushort4 ob = { f2b(o.x), f2b(o.y), f2b(o.z), f2b(o.w) };
        *(ushort4*)(outb + (long)row * H + lane * 4) = ob;
    }
}

// ---------------- conversions ----------------
__global__ __launch_bounds__(256) void xcast_kernel(const float* __restrict__ x,
                                                    ushort* __restrict__ xb)
{
    long i = (long)blockIdx.x * 256 + threadIdx.x;
    if (i >= (long)NN * KIN) return;
    int n = (int)(i / KIN), c = (int)(i % KIN);
    xb[i] = (c < FIN) ? f2b(x[(long)n * FIN + c]) : (ushort)0;
}

__global__ __launch_bounds__(256) void wtin_kernel(const float* __restrict__ W,
                                                   ushort* __restrict__ Wt)
{
    int i = blockIdx.x * 256 + threadIdx.x;
    if (i >= 256 * KIN) return;
    int m = i / KIN, k = i % KIN;
    Wt[i] = (k < FIN) ? f2b(W[(long)k * H + m]) : (ushort)0;
}

__global__ __launch_bounds__(256) void wtqkv_kernel(
    const float* __restrict__ Wq, const float* __restrict__ Wk,
    const float* __restrict__ Wv, ushort* __restrict__ out)
{
    long i = (long)blockIdx.x * 256 + threadIdx.x;
    if (i >= (long)LAYERS * 768 * 256) return;
    int l = (int)(i / (768 * 256));
    int r = (int)(i % (768 * 256));
    int m = r >> 8, k = r & 255;
    const float* W = (m < 256) ? Wq : ((m < 512) ? Wk : Wv);
    out[i] = f2b(W[(long)l * 65536 + (long)k * 256 + (m & 255)]);
}

__global__ __launch_bounds__(256) void wtgen_kernel(
    const float* __restrict__ W, ushort* __restrict__ out, int L, int K, int M)
{
    long i = (long)blockIdx.x * 256 + threadIdx.x;
    if (i >= (long)L * K * M) return;
    int l = (int)(i / ((long)K * M));
    int r = (int)(i % ((long)K * M));
    int m = r / K, k = r % K;
    out[i] = f2b(W[(long)l * K * M + (long)k * M + m]);
}

// ---------------- CSR build ----------------
__global__ __launch_bounds__(256) void deg_kernel(const int* __restrict__ dst,
                                                   int* __restrict__ deg)
{
    int e = blockIdx.x * 256 + threadIdx.x;
    if (e >= NE) return;
    atomicAdd(&deg[dst[e]], 1);
}

__global__ __launch_bounds__(256) void scan1_kernel(const int* __restrict__ deg,
                                                     int* __restrict__ rowptr,
                                                     int* __restrict__ bsum)
{
    __shared__ int buf[256];
    int tid = threadIdx.x;
    int i = blockIdx.x * 256 + tid;
    int v = (i < NN) ? deg[i] : 0;
    buf[tid] = v;
    __syncthreads();
    #pragma unroll
    for (int off = 1; off < 256; off <<= 1) {
        int t = (tid >= off) ? buf[tid - off] : 0;
        __syncthreads();
        buf[tid] += t;
        __syncthreads();
    }
    if (i < NN) rowptr[i] = buf[tid] - v;
    if (tid == 255) bsum[blockIdx.x] = buf[255];
}

__global__ __launch_bounds__(256) void scan2_kernel(int* __restrict__ bsum, int nb)
{
    __shared__ int buf[256];
    int tid = threadIdx.x;
    int v = (tid < nb) ? bsum[tid] : 0;
    buf[tid] = v;
    __syncthreads();
    #pragma unroll
    for (int off = 1; off < 256; off <<= 1) {
        int t = (tid >= off) ? buf[tid - off] : 0;
        __syncthreads();
        buf[tid] += t;
        __syncthreads();
    }
    if (tid < nb) bsum[tid] = buf[tid] - v;
}

__global__ __launch_bounds__(256) void scan3_kernel(int* __restrict__ rowptr,
                                                     const int* __restrict__ bsum)
{
    int i = blockIdx.x * 256 + threadIdx.x;
    if (i < NN) rowptr[i] += bsum[blockIdx.x];
    if (i == 0) rowptr[NN] = NE;
}

__global__ __launch_bounds__(256) void fill_kernel(
    const int* __restrict__ src, const int* __restrict__ dst,
    const float* __restrict__ ea, const int* __restrict__ rowptr,
    int* __restrict__ cursor, int* __restrict__ csr_src,
    float2* __restrict__ csr_ea)
{
    int e = blockIdx.x * 256 + threadIdx.x;
    if (e >= NE) return;
    int d = dst[e];
    int pos = atomicAdd(&cursor[d], 1);
    int j = rowptr[d] + pos;
    csr_src[j] = src[e];
    csr_ea[j] = *(const float2*)(ea + 2 * e);
}

// ---------------- fused gather attention (one wave per node, all 8 heads) ----------------
// Depth-4 register prefetch, pairwise softmax, exp2-domain. Pinned at the
// random-gather L2-fill ceiling (~3.4 TB/s, FETCH 392MB constant across
// depth-2/depth-4/sorted variants). Only byte-reduction (fp8 K/V) remains --
// absmax-risky, parked.
#define LOADE(idx, kbuf, vbuf, ebuf)                                   \
    { int s_ = csr_src[idx]; ebuf = csr_ea[idx];                       \
      const ushort* kr_ = qkv + (long)s_ * 768 + 256;                  \
      kbuf = *(const uint2*)(kr_ + lane * 4);                          \
      vbuf = *(const uint2*)(kr_ + 256 + lane * 4); }

#define PAIR(k1, v1, e1, k2, v2, e2)                                               \
    { float p1 = dot2b(q2.x, (k1).x) + dot2b(q2.y, (k1).y);                        \
      float p2 = dot2b(q2.x, (k2).x) + dot2b(q2.y, (k2).y);                        \
      p1 += __shfl_xor(p1, 1);  p2 += __shfl_xor(p2, 1);                           \
      p1 += __shfl_xor(p1, 2);  p2 += __shfl_xor(p2, 2);                           \
      p1 += __shfl_xor(p1, 4);  p2 += __shfl_xor(p2, 4);                           \
      float s1 = p1 * c1 + (e1).x * w0 + (e1).y * w1 + bb;                         \
      float s2 = p2 * c1 + (e2).x * w0 + (e2).y * w1 + bb;                         \
      float mp = fmaxf(s1, s2);                                                    \
      float x1 = __builtin_amdgcn_exp2f(s1 - mp);                                  \
      float x2 = __builtin_amdgcn_exp2f(s2 - mp);                                  \
      float lp = x1 + x2;                                                          \
      float b0 = x1 * __uint_as_float((v1).x << 16)         + x2 * __uint_as_float((v2).x << 16);          \
      float b1 = x1 * __uint_as_float((v1).x & 0xffff0000u) + x2 * __uint_as_float((v2).x & 0xffff0000u);  \
      float b2 = x1 * __uint_as_float((v1).y << 16)         + x2 * __uint_as_float((v2).y << 16);          \
      float b3 = x1 * __uint_as_float((v1).y & 0xffff0000u) + x2 * __uint_as_float((v2).y & 0xffff0000u);  \
      float mn = fmaxf(m, mp);                                                     \
      float so = __builtin_amdgcn_exp2f(m - mn);                                   \
      float sp = __builtin_amdgcn_exp2f(mp - mn);                                  \
      l  = l  * so + lp * sp;                                                      \
      a0 = a0 * so + b0 * sp;                                                      \
      a1 = a1 * so + b1 * sp;                                                      \
      a2 = a2 * so + b2 * sp;                                                      \
      a3 = a3 * so + b3 * sp;                                                      \
      m = mn; }

#define SINGLE(kb, vb, eb)                                                         \
    { float p1 = dot2b(q2.x, (kb).x) + dot2b(q2.y, (kb).y);                        \
      p1 += __shfl_xor(p1, 1);                                                     \
      p1 += __shfl_xor(p1, 2);                                                     \
      p1 += __shfl_xor(p1, 4);                                                     \
      float s1 = p1 * c1 + (eb).x * w0 + (eb).y * w1 + bb;                         \
      float mn = fmaxf(m, s1);                                                     \
      float so = __builtin_amdgcn_exp2f(m - mn);                                   \
      float e_ = __builtin_amdgcn_exp2f(s1 - mn);                                  \
      l  = l  * so + e_;                                                           \
      a0 = a0 * so + e_ * __uint_as_float((vb).x << 16);                           \
      a1 = a1 * so + e_ * __uint_as_float((vb).x & 0xffff0000u);                   \
      a2 = a2 * so + e_ * __uint_as_float((vb).y << 16);                           \
      a3 = a3 * so + e_ * __uint_as_float((vb).y & 0xffff0000u);                   \
      m = mn; }

__global__ __launch_bounds__(256) void attn_kernel(
    const ushort* __restrict__ qkv,
    const int* __restrict__ rowptr, const int* __restrict__ csr_src,
    const float2* __restrict__ csr_ea,
    const float* __restrict__ We, const float* __restrict__ be,
    ushort* __restrict__ aggb)
{
    int node = blockIdx.x * 4 + (threadIdx.x >> 6);
    if (node >= NN) return;
    int lane = threadIdx.x & 63;
    int h = lane >> 3;                 // global head 0..7
    const float L2E = 1.4426950408889634f;
    float w0 = We[h] * L2E, w1 = We[8 + h] * L2E, bb = be[h] * L2E;
    const float c1 = INV_SCALE * L2E;

    uint2 q2 = *(const uint2*)(qkv + (long)node * 768 + lane * 4);
    int jbeg = rowptr[node], jend = rowptr[node + 1];

    float m = -1e30f, l = 0.f;
    float a0 = 0.f, a1 = 0.f, a2 = 0.f, a3 = 0.f;

    uint2 k0v = {0,0}, v0v = {0,0}, k1v = {0,0}, v1v = {0,0};
    uint2 k2v = {0,0}, v2v = {0,0}, k3v = {0,0}, v3v = {0,0};
    float2 e0v = {0.f,0.f}, e1v = {0.f,0.f}, e2v = {0.f,0.f}, e3v = {0.f,0.f};

    if (jbeg + 0 < jend) LOADE(jbeg + 0, k0v, v0v, e0v);
    if (jbeg + 1 < jend) LOADE(jbeg + 1, k1v, v1v, e1v);
    if (jbeg + 2 < jend) LOADE(jbeg + 2, k2v, v2v, e2v);
    if (jbeg + 3 < jend) LOADE(jbeg + 3, k3v, v3v, e3v);

    int j = jbeg;
    for (; j + 3 < jend; j += 4) {
        PAIR(k0v, v0v, e0v, k1v, v1v, e1v);          // edges j, j+1
        if (j + 4 < jend) LOADE(j + 4, k0v, v0v, e0v);
        if (j + 5 < jend) LOADE(j + 5, k1v, v1v, e1v);
        PAIR(k2v, v2v, e2v, k3v, v3v, e3v);          // edges j+2, j+3
        if (j + 6 < jend) LOADE(j + 6, k2v, v2v, e2v);
        if (j + 7 < jend) LOADE(j + 7, k3v, v3v, e3v);
    }
    int rleft = jend - j;                            // 0..3
    if (rleft >= 2) PAIR(k0v, v0v, e0v, k1v, v1v, e1v);
    if (rleft == 3) SINGLE(k2v, v2v, e2v);
    if (rleft == 1) SINGLE(k0v, v0v, e0v);

    float inv = 1.0f / (l + 1e-16f);
    ushort4 o = { f2b(a0 * inv), f2b(a1 * inv), f2b(a2 * inv), f2b(a3 * inv) };
    *(ushort4*)(aggb + (long)node * 256 + lane * 4) = o;
}

// ---------------- classifier tail ----------------
__global__ __launch_bounds__(256) void cls_kernel(
    const float* __restrict__ t1, const float* __restrict__ W,
    const float* __restrict__ b, float* __restrict__ out)
{
    int i = blockIdx.x * 256 + threadIdx.x;
    if (i >= NN) return;
    const float* tp = t1 + (long)i * 128;
    float a0 = 0.f, a1 = 0.f;
    #pragma unroll
    for (int j = 0; j < 128; j += 4) {
        float4 t = *(const float4*)(tp + j);
        a0 += t.x * W[(j + 0) * 2] + t.y * W[(j + 1) * 2] + t.z * W[(j + 2) * 2] + t.w * W[(j + 3) * 2];
        a1 += t.x * W[(j + 0) * 2 + 1] + t.y * W[(j + 1) * 2 + 1] + t.z * W[(j + 2) * 2 + 1] + t.w * W[(j + 3) * 2 + 1];
    }
    float l0 = a0 + b[0], l1 = a1 + b[1];
    out[(long)i * 2 + 0] = l0;
    out[(long)i * 2 + 1] = l1;
    float mx = fmaxf(l0, l1);
    float p0 = expf(l0 - mx), p1 = expf(l1 - mx);
    float sden = p0 + p1;
    out[2L * NN + (long)i * 2 + 0] = p0 / sden;
    out[2L * NN + (long)i * 2 + 1] = p1 / sden;
}

extern "C" void kernel_launch(void* const* d_in, const int* in_sizes, int n_in,
                              void* d_out, int out_size, void* d_ws, size_t ws_size,
                              hipStream_t stream) {
    const float* x      = (const float*)d_in[0];
    const int*   ei     = (const int*)d_in[1];
    const float* ea     = (const float*)d_in[2];
    const float* in_W   = (const float*)d_in[3];
    const float* in_b   = (const float*)d_in[4];
    const float* in_g   = (const float*)d_in[5];
    const float* in_bb  = (const float*)d_in[6];
    const float* Wq     = (const float*)d_in[7];
    const float* Wk     = (const float*)d_in[8];
    const float* Wv     = (const float*)d_in[9];
    const float* We     = (const float*)d_in[10];
    const float* be     = (const float*)d_in[11];
    const float* Wo     = (const float*)d_in[12];
    const float* bo     = (const float*)d_in[13];
    const float* ln1_g  = (const float*)d_in[14];
    const float* ln1_b  = (const float*)d_in[15];
    const float* ln2_g  = (const float*)d_in[16];
    const float* ln2_b  = (const float*)d_in[17];
    const float* f1_W   = (const float*)d_in[18];
    const float* f1_b   = (const float*)d_in[19];
    const float* f2_W   = (const float*)d_in[20];
    const float* f2_b   = (const float*)d_in[21];
    const float* cls1_W = (const float*)d_in[22];
    const float* cls1_b = (const float*)d_in[23];
    const float* cls2_W = (const float*)d_in[24];
    const float* cls2_b = (const float*)d_in[25];
    float* out = (float*)d_out;

    const int* src = ei;
    const int* dst = ei + NE;

    // ---- workspace layout (~197 MB) ----
    char* w = (char*)d_ws;
    float* B0 = (float*)w;            w += (size_t)NN * H * 4;       // h / out (fp32)
    ushort* hb = (ushort*)w;          w += (size_t)NN * H * 2;       // bf16 activations
    char* pool = w;                   w += (size_t)NN * 1024 * 2;    // 102.4 MB union
    ushort* qkv  = (ushort*)pool;                                    // N x 768 bf16
    ushort* aggb = (ushort*)(pool + (size_t)NN * 768 * 2);           // N x 256 bf16
    float*  tproj = (float*)pool;                                    // input-proj t
    ushort* xb   = (ushort*)(pool + (size_t)NN * H * 4);             // N x 224 bf16
    ushort* tb   = (ushort*)pool;                                    // FFN N x 1024 bf16
    float*  t1   = (float*)pool;                                     // cls hidden fp32
    int* deg    = (int*)w;            w += (size_t)NN * 4;
    int* cursor = (int*)w;            w += (size_t)NN * 4;
    int* rowptr = (int*)w;            w += (size_t)(NN + 2) * 4;
    int* bsum   = (int*)w;            w += 1024;
    int* csr_src = (int*)w;           w += (size_t)NE * 4;
    float2* csr_ea = (float2*)w;      w += (size_t)NE * 8;
    ushort* wqkv_t = (ushort*)w;      w += (size_t)LAYERS * 768 * 256 * 2;
    ushort* wo_t  = (ushort*)w;       w += (size_t)LAYERS * 65536 * 2;
    ushort* f1_t  = (ushort*)w;       w += (size_t)LAYERS * 262144 * 2;
    ushort* f2_t  = (ushort*)w;       w += (size_t)LAYERS * 262144 * 2;
    ushort* c1_t  = (ushort*)w;       w += (size_t)32768 * 2;
    ushort* inw_t = (ushort*)w;       w += (size_t)256 * KIN * 2;

    dim3 blk(256);
    const int ln_grid = (NN + 3) / 4;
    const int e_grid = (NE + 255) / 256;
    const int n_grid = (NN + 255) / 256;
    const int ty = (NN + 127) / 128;   // 128-row tiles

    // ---- CSR build ----
    hipMemsetAsync(deg, 0, (size_t)NN * 4, stream);
    hipMemsetAsync(cursor, 0, (size_t)NN * 4, stream);
    deg_kernel<<<e_grid, blk, 0, stream>>>(dst, deg);
    scan1_kernel<<<n_grid, blk, 0, stream>>>(deg, rowptr, bsum);
    scan2_kernel<<<1, blk, 0, stream>>>(bsum, n_grid);
    scan3_kernel<<<n_grid, blk, 0, stream>>>(rowptr, bsum);
    fill_kernel<<<e_grid, blk, 0, stream>>>(src, dst, ea, rowptr, cursor, csr_src, csr_ea);

    // ---- weight convert/transpose ----
    wtqkv_kernel<<<(int)(((long)LAYERS * 768 * 256 + 255) / 256), blk, 0, stream>>>(Wq, Wk, Wv, wqkv_t);
    wtgen_kernel<<<(int)(((long)LAYERS * 65536 + 255) / 256), blk, 0, stream>>>(Wo, wo_t, LAYERS, 256, 256);
    wtgen_kernel<<<(int)(((long)LAYERS * 262144 + 255) / 256), blk, 0, stream>>>(f1_W, f1_t, LAYERS, 256, 1024);
    wtgen_kernel<<<(int)(((long)LAYERS * 262144 + 255) / 256), blk, 0, stream>>>(f2_W, f2_t, LAYERS, 1024, 256);
    wtgen_kernel<<<(32768 + 255) / 256, blk, 0, stream>>>(cls1_W, c1_t, 1, 256, 128);
    wtin_kernel<<<(256 * KIN + 255) / 256, blk, 0, stream>>>(in_W, inw_t);

    // ---- input projection (MFMA) ----
    xcast_kernel<<<(int)(((long)NN * KIN + 255) / 256), blk, 0, stream>>>(x, xb);
    {
        gemm_bf16_kernel<<<2 * ty, blk, 0, stream>>>(xb, KIN, inw_t, in_b, nullptr, 0,
                                                     tproj, nullptr, H, NN, KIN, 0, 2);
        ln256_kernel<<<ln_grid, blk, 0, stream>>>(tproj, nullptr, nullptr, in_g, in_bb, B0, nullptr, NN, 1);
    }

    for (int l = 0; l < LAYERS; ++l) {
        const float* we  = We + (long)l * 16;
        const float* bel = be + (long)l * 8;
        const float* bol = bo + (long)l * H;
        const float* g1 = ln1_g + (long)l * H;
        const float* b1 = ln1_b + (long)l * H;
        const float* g2 = ln2_g + (long)l * H;
        const float* b2 = ln2_b + (long)l * H;
        const float* bf1 = f1_b + (long)l * FF;
        const float* bf2 = f2_b + (long)l * H;

        // hb = bf16(LN1(h))
        ln256_kernel<<<ln_grid, blk, 0, stream>>>(B0, nullptr, nullptr, g1, b1, nullptr, hb, NN, 0);

        // fused QKV (M=768) + 8-head gather attention
        gemm_bf16_kernel<<<6 * ty, blk, 0, stream>>>(hb, H, wqkv_t + (long)l * 768 * 256,
            nullptr, nullptr, 0, nullptr, qkv, 768, NN, H, 0, 6);
        attn_kernel<<<(NN + 3) / 4, blk, 0, stream>>>(qkv, rowptr, csr_src, csr_ea, we, bel, aggb);

        // B0 = LN(aggb@Wo^T + bo + h); hb = bf16(out)
        gemm_bf16_kernel<<<2 * ty, blk, 0, stream>>>(aggb, H, wo_t + (long)l * 65536,
            bol, nullptr, 0, nullptr, qkv, H, NN, H, 0, 2);   // reuse qkv head as woo
        ln256_kernel<<<ln_grid, blk, 0, stream>>>(nullptr, qkv, B0, g2, b2, B0, hb, NN, 0);

        // FFN one-shot: tb = gelu(hb@f1^T+b) bf16 ; B0 = tb@f2^T + b + B0
        gemm_bf16_kernel<<<8 * ty, blk, 0, stream>>>(hb, H, f1_t + (long)l * 262144,
            bf1, nullptr, 0, nullptr, tb, FF, NN, H, 1, 8);
        gemm_bf16_kernel<<<2 * ty, blk, 0, stream>>>(tb, FF, f2_t + (long)l * 262144,
            bf2, B0, H, B0, (l == LAYERS - 1) ? hb : nullptr, H, NN, FF, 0, 2);
    }

    // ---- classifier ----
    {
        gemm_bf16_kernel<<<1 * ty, blk, 0, stream>>>(hb, H, c1_t, cls1_b, nullptr, 0,
                                                     t1, nullptr, 128, NN, H, 1, 1);
        cls_kernel<<<n_grid, blk, 0, stream>>>(t1, cls2_W, cls2_b, out);
    }
}